// Round 2
// baseline (1144.886 us; speedup 1.0000x reference)
//
#include <hip/hip_runtime.h>
#include <hip/hip_bf16.h>

#define DIM 256
#define WIN 64
#define HEADS 8
#define HD 32
#define NW 64

typedef __attribute__((ext_vector_type(8))) short bf16x8;
typedef __attribute__((ext_vector_type(4))) float f32x4;

// LDS strides (unsigned short elements). All GEMM-read row strides are
// multiples of 8 shorts (16 B) so ds_read_b128 stays 16B-aligned.
//   XS=264 -> 528B row: bank step 4, 2-way on b128 (free)
//   QS=40  ->  80B row: bank step 20, 2-way (free)
//   VS=72  -> 144B row: bank step 4,  2-way (free)
//   PS=72  -> overlays q+k region (64*72 <= 64*80)
//   SS=72  -> attn-out stage
#define XS 264
#define QS 40
#define VS 72
#define PS 72
#define SS 72
#define HREG (2 * 64 * QS + 32 * VS)               // 7424 shorts per head slot
#define LDS_ELEMS (WIN * XS + 2 * HREG + 64 * SS)  // 36352 shorts = 72704 B
                                                   // 2 blocks/CU (145.4 KB < 160 KB)

__device__ __forceinline__ unsigned short f2bf(float f) {
  union { float f; unsigned u; } v; v.f = f;
  unsigned r = v.u + 0x7FFFu + ((v.u >> 16) & 1u);   // RNE
  return (unsigned short)(r >> 16);
}

__device__ __forceinline__ bf16x8 ldf(const unsigned short* p) {
  return *reinterpret_cast<const bf16x8*>(p);
}

#define MFMA16(a, b, c) __builtin_amdgcn_mfma_f32_16x16x32_bf16(a, b, c, 0, 0, 0)

// ---------------------------------------------------------------------------
// Prep: transpose+convert weights to bf16 (fold softmax scale into q cols),
// scale q bias, and pre-fuse rel-pos bias + mask into rbm[w][h][n][m] (f32)
// when workspace allows (falls back to rb[h][n][m] + in-kernel mask add).
// ---------------------------------------------------------------------------
__global__ void prep_kernel(const float* __restrict__ w_qkv,
                            const float* __restrict__ b_qkv,
                            const float* __restrict__ w_proj,
                            const float* __restrict__ bias_table,
                            const float* __restrict__ mask,
                            unsigned short* __restrict__ wqkv_t,   // [768][256]
                            unsigned short* __restrict__ wproj_t,  // [256][256]
                            float* __restrict__ bqkv_s,            // [768]
                            float* __restrict__ rbp,               // rbm or rb
                            int use_rbm) {
  const float SCALE = 0.1767766952966369f;  // 32^-0.5
  int idx = blockIdx.x * blockDim.x + threadIdx.x;
  if (idx < 768 * 256) {
    int n = idx >> 8, k = idx & 255;
    float v = w_qkv[k * 768 + n];
    if (n < 256) v *= SCALE;               // q columns get the scale
    wqkv_t[idx] = f2bf(v);
  }
  if (idx < 256 * 256) {
    int n = idx >> 8, k = idx & 255;
    wproj_t[idx] = f2bf(w_proj[k * 256 + n]);
  }
  if (idx < 768) {
    float v = b_qkv[idx];
    if (idx < 256) v *= SCALE;
    bqkv_s[idx] = v;
  }
  if (use_rbm) {
    if (idx < NW * HEADS * WIN * WIN) {    // 2,097,152
      int w = idx >> 15;
      int h = (idx >> 12) & 7;
      int n = (idx >> 6) & 63;
      int m = idx & 63;
      rbp[idx] = bias_table[(n - m + WIN - 1) * HEADS + h] + mask[w * 4096 + n * 64 + m];
    }
  } else {
    if (idx < HEADS * WIN * WIN) {
      int h = idx >> 12;
      int r = idx & 4095;
      int n = r >> 6, m = r & 63;
      rbp[idx] = bias_table[(n - m + WIN - 1) * HEADS + h];
    }
  }
}

// ---------------------------------------------------------------------------
// Fused window attention: one block per window, 8 waves, 512 threads,
// 4 passes x 2 heads. Proj is accumulated in registers across passes
// (out = sum_h attnout_h @ Wproj[h*32:...]), so no 64x256 out buffer in LDS.
// LDS 72.7 KB -> 2 blocks/CU: independent barrier domains overlap phases.
// ---------------------------------------------------------------------------
__global__ __launch_bounds__(512, 4) void fused_attn(
    const float* __restrict__ x,          // [4096][64][256]
    const float* __restrict__ mask,       // [64][64][64] (fallback only)
    const float* __restrict__ b_proj,     // [256]
    const unsigned short* __restrict__ wqkv_t,   // [768][256] bf16
    const unsigned short* __restrict__ wproj_t,  // [256][256] bf16
    const float* __restrict__ bqkv_s,     // [768]
    const float* __restrict__ rbp,        // rbm [64][8][64][64] or rb [8][64][64]
    float* __restrict__ out,              // [4096][64][256]
    int use_rbm) {
  extern __shared__ unsigned short lds[];
  unsigned short* xs = lds;                                   // [64][XS]
  const int tid = threadIdx.x;
  const int wave = tid >> 6;
  const int lane = tid & 63;
  const int l16 = lane & 15;
  const int quad = lane >> 4;
  const int b = blockIdx.x;

  const f32x4 zf = {0.f, 0.f, 0.f, 0.f};

  // S/PV-phase role: wave = (h2, rt) -> head-in-pass h2, 16-row strip rt
  const int h2 = wave >> 2;
  const int rt = wave & 3;
  // qkv-phase role: wave = (h2, rhalf, cg) -> 32-row half, 3-coltile group
  const int rhalf = (wave >> 1) & 1;
  const int cg = wave & 1;

  unsigned short* hbase = lds + WIN * XS;         // 2 head slots of HREG
  unsigned short* stage = hbase + 2 * HREG;       // [64][SS] attn-out (2 heads)

  unsigned short* qh = hbase + h2 * HREG;         // [64][QS]
  unsigned short* kh = qh + 64 * QS;              // [64][QS]
  unsigned short* vth = qh + 2 * 64 * QS;         // [32][VS]
  unsigned short* ph = qh;                        // [64][PS] overlays q,k

  // persistent projection accumulator: wave owns output cols [wave*32, +32)
  f32x4 pacc[2][4];
#pragma unroll
  for (int c2 = 0; c2 < 2; ++c2)
#pragma unroll
    for (int r2 = 0; r2 < 4; ++r2) pacc[c2][r2] = zf;

  // ---- Phase 0: load x window -> LDS bf16 ----
  const float4* xg = reinterpret_cast<const float4*>(x + (size_t)b * (WIN * DIM));
#pragma unroll
  for (int i = 0; i < 8; ++i) {
    int e = tid + i * 512;             // float4 index, 4096 total
    float4 f = xg[e];
    int n = e >> 6;
    int c = (e & 63) << 2;
    ushort4 s4;
    s4.x = f2bf(f.x); s4.y = f2bf(f.y); s4.z = f2bf(f.z); s4.w = f2bf(f.w);
    *reinterpret_cast<ushort4*>(xs + n * XS + c) = s4;
  }
  __syncthreads();

#pragma unroll 1
  for (int p = 0; p < 4; ++p) {
    // ---- qkv GEMM for heads {2p, 2p+1}: wave (h2, rhalf, cg) computes
    //      rows [rhalf*32,+32) x 3 col-tiles {cg*3..cg*3+2} of head 2p+h2.
    //      Each col-tile loaded by 2 waves (the two row halves): 2x L2, but
    //      A-reads are row-private (no 16x broadcast re-read of xs).
    {
      unsigned short* qhw = hbase + h2 * HREG;
      unsigned short* khw = qhw + 64 * QS;
      unsigned short* vthw = qhw + 2 * 64 * QS;
      const int hq = p * 2 + h2;
      f32x4 qacc[3][2];
#pragma unroll
      for (int c = 0; c < 3; ++c)
#pragma unroll
        for (int rh = 0; rh < 2; ++rh) qacc[c][rh] = zf;

#pragma unroll
      for (int kk = 0; kk < 8; ++kk) {
        int k0 = kk * 32 + quad * 8;
        bf16x8 a0 = ldf(xs + (rhalf * 32 + l16) * XS + k0);
        bf16x8 a1 = ldf(xs + (rhalf * 32 + 16 + l16) * XS + k0);
#pragma unroll
        for (int c = 0; c < 3; ++c) {
          int ctp = cg * 3 + c;
          int cbase = hq * 32 + (ctp >> 1) * 256 + (ctp & 1) * 16;
          bf16x8 bb = ldf(wqkv_t + (cbase + l16) * 256 + k0);
          qacc[c][0] = MFMA16(a0, bb, qacc[c][0]);
          qacc[c][1] = MFMA16(a1, bb, qacc[c][1]);
        }
      }
#pragma unroll
      for (int c = 0; c < 3; ++c) {
        int ctp = cg * 3 + c;
        int cbase = hq * 32 + (ctp >> 1) * 256 + (ctp & 1) * 16;
        float bias = bqkv_s[cbase + l16];
#pragma unroll
        for (int rh = 0; rh < 2; ++rh)
#pragma unroll
          for (int r = 0; r < 4; ++r) {
            int row = rhalf * 32 + rh * 16 + quad * 4 + r;
            unsigned short bv = f2bf(qacc[c][rh][r] + bias);
            if (ctp < 2)      qhw[row * QS + ctp * 16 + l16] = bv;
            else if (ctp < 4) khw[row * QS + (ctp - 2) * 16 + l16] = bv;
            else              vthw[((ctp - 4) * 16 + l16) * VS + row] = bv;
          }
      }
    }
    __syncthreads();   // B1: q,k,vt of both heads visible

    // ---- S = q @ k^T for wave's 16-row strip of head 2p+h2 ----
    const int h = p * 2 + h2;
    f32x4 sacc[4];
    {
      bf16x8 a = ldf(qh + (rt * 16 + l16) * QS + quad * 8);
#pragma unroll
      for (int ct = 0; ct < 4; ++ct) {
        bf16x8 bb = ldf(kh + (ct * 16 + l16) * QS + quad * 8);
        sacc[ct] = MFMA16(a, bb, zf);
      }
    }
    __syncthreads();   // B1b: all q/k reads complete before P overlays them

    // ---- softmax (+pre-fused bias+mask), P -> LDS overlay ----
    {
      const float* rbw;
      const float* mw = nullptr;
      if (use_rbm) {
        rbw = rbp + ((size_t)((b & (NW - 1)) * HEADS + h)) * 4096;
      } else {
        rbw = rbp + h * 4096;
        mw = mask + (size_t)(b & (NW - 1)) * 4096;
      }
#pragma unroll
      for (int r = 0; r < 4; ++r) {
        int row = rt * 16 + quad * 4 + r;
        float vals[4];
#pragma unroll
        for (int ct = 0; ct < 4; ++ct) {
          int col = ct * 16 + l16;
          float add = use_rbm ? rbw[row * 64 + col]
                              : (rbw[row * 64 + col] + mw[row * 64 + col]);
          vals[ct] = sacc[ct][r] + add;
        }
        float m = fmaxf(fmaxf(vals[0], vals[1]), fmaxf(vals[2], vals[3]));
#pragma unroll
        for (int o = 1; o < 16; o <<= 1) m = fmaxf(m, __shfl_xor(m, o, 64));
        float s = 0.f;
#pragma unroll
        for (int ct = 0; ct < 4; ++ct) { vals[ct] = __expf(vals[ct] - m); s += vals[ct]; }
#pragma unroll
        for (int o = 1; o < 16; o <<= 1) s += __shfl_xor(s, o, 64);
        float inv = 1.0f / s;
#pragma unroll
        for (int ct = 0; ct < 4; ++ct)
          ph[row * PS + ct * 16 + l16] = f2bf(vals[ct] * inv);
      }
    }
    // P rows are wave-private between softmax and PV: no sync needed.

    // ---- O = P @ v (wave: its 16 rows x 32 dims) -> stage bf16 ----
    {
      f32x4 oacc[2] = {zf, zf};
#pragma unroll
      for (int km = 0; km < 2; ++km) {
        int k0 = km * 32 + quad * 8;
        bf16x8 a = ldf(ph + (rt * 16 + l16) * PS + k0);
#pragma unroll
        for (int jt = 0; jt < 2; ++jt) {
          bf16x8 bb = ldf(vth + (jt * 16 + l16) * VS + k0);
          oacc[jt] = MFMA16(a, bb, oacc[jt]);
        }
      }
#pragma unroll
      for (int jt = 0; jt < 2; ++jt)
#pragma unroll
        for (int r = 0; r < 4; ++r) {
          int row = rt * 16 + quad * 4 + r;
          stage[row * SS + h2 * 32 + jt * 16 + l16] = f2bf(oacc[jt][r]);
        }
    }
    __syncthreads();   // B2: stage (both heads) complete

    // ---- proj partial: pacc += attnout[:, pass 64 dims] @ Wproj[slice] ----
    {
#pragma unroll
      for (int hb = 0; hb < 2; ++hb) {
        int hh = p * 2 + hb;
        bf16x8 bb[2];
#pragma unroll
        for (int c2 = 0; c2 < 2; ++c2) {
          int ct = wave * 2 + c2;
          bb[c2] = ldf(wproj_t + (ct * 16 + l16) * 256 + hh * 32 + quad * 8);
        }
#pragma unroll
        for (int r2 = 0; r2 < 4; ++r2) {
          bf16x8 a = ldf(stage + (r2 * 16 + l16) * SS + hb * 32 + quad * 8);
#pragma unroll
          for (int c2 = 0; c2 < 2; ++c2)
            pacc[c2][r2] = MFMA16(a, bb[c2], pacc[c2][r2]);
        }
      }
    }
    // no barrier needed before next pass: next writers of stage/q/k/vt all
    // sit behind next pass's B1/B1b; proj reads complete before any wave
    // reaches them.
  }

  // ---- epilogue: out = pacc + bias ----
#pragma unroll
  for (int c2 = 0; c2 < 2; ++c2) {
    int col = wave * 32 + c2 * 16 + l16;
    float bias = b_proj[col];
#pragma unroll
    for (int r2 = 0; r2 < 4; ++r2)
#pragma unroll
      for (int r = 0; r < 4; ++r) {
        int row = r2 * 16 + quad * 4 + r;
        out[(size_t)(b * WIN + row) * DIM + col] = pacc[c2][r2][r] + bias;
      }
  }
}

extern "C" void kernel_launch(void* const* d_in, const int* in_sizes, int n_in,
                              void* d_out, int out_size, void* d_ws, size_t ws_size,
                              hipStream_t stream) {
  const float* x          = (const float*)d_in[0];
  const float* mask       = (const float*)d_in[1];
  const float* w_qkv      = (const float*)d_in[2];
  const float* b_qkv      = (const float*)d_in[3];
  const float* w_proj     = (const float*)d_in[4];
  const float* b_proj     = (const float*)d_in[5];
  const float* bias_table = (const float*)d_in[6];

  // workspace layout (bytes):
  //   wqkv_t 393216 | wproj_t 131072 | bqkv_s 3072 | rbm 8388608 (or rb 131072)
  unsigned short* wqkv_t  = (unsigned short*)d_ws;
  unsigned short* wproj_t = wqkv_t + 768 * 256;
  float* bqkv_s           = (float*)(wproj_t + 256 * 256);
  float* rbp              = bqkv_s + 768;

  const size_t need_rbm = 527360 + (size_t)NW * HEADS * WIN * WIN * 4;  // ~8.9 MB
  int use_rbm = (ws_size >= need_rbm) ? 1 : 0;
  int pgrid = use_rbm ? 8192 : 768;   // rbm needs 2M threads

  prep_kernel<<<pgrid, 256, 0, stream>>>(w_qkv, b_qkv, w_proj, bias_table, mask,
                                         wqkv_t, wproj_t, bqkv_s, rbp, use_rbm);

  (void)hipFuncSetAttribute((const void*)fused_attn,
                            hipFuncAttributeMaxDynamicSharedMemorySize,
                            LDS_ELEMS * 2);
  fused_attn<<<4096, 512, LDS_ELEMS * 2, stream>>>(
      x, mask, b_proj, wqkv_t, wproj_t, bqkv_s, rbp, (float*)d_out, use_rbm);
}